// Round 11
// baseline (195.782 us; speedup 1.0000x reference)
//
#include <hip/hip_runtime.h>

#define GH 64
#define LS 32
#define HF 32
#define DS 16

// transcendental folding constants (exact fp32 rescale of weights at prep)
#define NLOG2E -1.4426950408889634f   // r,z columns:  sigm(x)=rcp(1+exp2(-log2e*x))
#define P2LOG2E 2.8853900817779268f   // n columns:    tanh(x)=1-2*rcp(exp2(2log2e*x)+1)

typedef short bf16x8 __attribute__((ext_vector_type(8)));
typedef float f32x4 __attribute__((ext_vector_type(4)));

#define MFMA16(a, b, c) __builtin_amdgcn_mfma_f32_16x16x32_bf16(a, b, c, 0, 0, 0)

__device__ __forceinline__ unsigned int f2bf_rne(float f) {
    unsigned int u = __float_as_uint(f);
    return (u + 0x7FFFu + ((u >> 16) & 1u)) >> 16;   // RNE (prep kernel only)
}
__device__ __forceinline__ unsigned short f2bf_h(float f) {
    return (unsigned short)((__float_as_uint(f) + 0x8000u) >> 16);  // half-up
}
__device__ __forceinline__ unsigned int pack_trunc(float v0, float v1) {
    return __builtin_amdgcn_perm(__float_as_uint(v1), __float_as_uint(v0),
                                 0x07060302u);   // (bf16(v1)<<16)|bf16(v0)
}
__device__ __forceinline__ bf16x8 as_frag(uint4 u) {
    union { uint4 a; bf16x8 b; } cv; cv.a = u; return cv.b;
}

// A-fragment from one 16x64 bf16 slot, XOR-swizzled 16B blocks:
// (seq,ch) at seq*64 + (((ch>>3)^(seq&7))<<3) + (ch&7). Conflict-free b128.
__device__ __forceinline__ bf16x8 ld_afrag(const unsigned short* slot, int m,
                                           int quad, int half) {
    int b   = half * 4 + quad;
    int idx = (m << 6) + ((b ^ (m & 7)) << 3);
    return as_frag(*reinterpret_cast<const uint4*>(slot + idx));
}

// ---- prep: fp32 weights -> bf16 MFMA B-fragments, fragment-ordered, with
// transcendental scales FOLDED IN. idx = rest*1024 + kc*512 + lane*8 + j.
// GRU (rest<96): rest=(l*6+mat)*4+jt, mat 0..2 = Wih r/z/n, 3..5 = Whh r/z/n.
// Epi (rest=96..103): rest=96+m2*4+jt, m2: 0=soW (unscaled), 1=s2sW.
__global__ __launch_bounds__(256) void prep_weights(
    const float* __restrict__ Wih, const float* __restrict__ Whh,
    const float* __restrict__ soW, const float* __restrict__ s2sW,
    unsigned short* __restrict__ wsW)
{
    int idx = blockIdx.x * 256 + threadIdx.x;
    if (idx >= 104 * 1024) return;
    int j = idx & 7, lane = (idx >> 3) & 63, kc = (idx >> 9) & 1, rest = idx >> 10;
    int k = kc * 32 + ((lane >> 4) << 3) + j;
    int c = lane & 15;
    float v;
    if (rest < 96) {
        int jt = rest & 3, mt = rest >> 2;
        int l = mt / 6, mat = mt - l * 6;
        int col = jt * 16 + c;
        const float* W = (mat < 3) ? Wih + (size_t)l * GH * 192
                                   : Whh + (size_t)l * GH * 192;
        int m3 = (mat < 3) ? mat : mat - 3;
        v = W[k * 192 + m3 * 64 + col];
        v *= (m3 == 2) ? P2LOG2E : NLOG2E;       // fold trans scale
    } else {
        int r2 = rest - 96;
        int jt = r2 & 3, m2 = r2 >> 2;
        int col = jt * 16 + c;
        v = (m2 ? s2sW : soW)[k * 64 + col];
        if (m2 && jt < 2) v *= NLOG2E;           // A_s sigmoid half
    }
    wsW[idx] = (unsigned short)f2bf_rne(v);
}

// Block = 8 waves x 64 = 512 thr; wave (jt = wid&3, ih = wid>>2). Twin waves
// (jt,0)/(jt,1) DUPLICATE the 12 MFMAs (MFMA pipe is ~20% busy - free) and
// split the 4 gate elements 2+2 (ih picks acc regs). Halves the per-wave
// transcendental chain (the measured bottleneck: exp2/rcp ~ 16 cyc/wave-op)
// and doubles waves/SIMD to 4 with perfectly balanced streams.
// hseq: RELU'D h (next-layer input), in-place across layers, 64 KB.
// hrec: PRE-relu h, 2-slot ping-pong (recurrence needs only t-1), 4 KB.
// One barrier/step; a(t+1) prefetched pre-barrier. Weights pre-scaled so exp2
// applies directly to the MFMA accumulator. Fused epilogue + fast SSM.
__global__ __launch_bounds__(512, 4) void slowfast_fused(
    const float* __restrict__ x,
    const float* __restrict__ siW,  const float* __restrict__ sib,
    const float* __restrict__ bih,  const float* __restrict__ bhh,
    const float* __restrict__ sob,  const float* __restrict__ s2sb,
    const float* __restrict__ finW, const float* __restrict__ finb,
    const float* __restrict__ foutW, const float* __restrict__ foutb,
    const unsigned short* __restrict__ wsW,
    float* __restrict__ out,
    int T, int ns, int BS)
{
    __shared__ __align__(16) unsigned short hseq[LS * 16 * 64];  // 64 KB
    __shared__ __align__(16) unsigned short hrec[2 * 16 * 64];   // 4 KB
    __shared__ float xs[16 * 33];    // x windows (pad-33)
    __shared__ float AG[16 * 65];    // A_s | g_s staging (pad-65)

    const int tid  = threadIdx.x;
    const int lane = tid & 63;
    const int wid  = tid >> 6;
    const int jt   = wid & 3;           // col tile
    const int ih   = wid >> 2;          // element half (acc regs 2*ih, 2*ih+1)
    const int c    = lane & 15;
    const int quad = lane >> 4;
    const int col  = jt * 16 + c;
    const int seqbase = blockIdx.x * 16;
    const uint4* wf = reinterpret_cast<const uint4*>(wsW);

    // ---- stage x windows (512 = one pass) ----
    {
        int seq = tid >> 5, t = tid & 31;
        int q = seqbase + seq; if (q > BS - 1) q = BS - 1;
        int b  = (q >= ns) ? 1 : 0;
        int si = q - b * ns;
        xs[seq * 33 + t] = x[b * T + si * DS + t];
    }
    __syncthreads();

    // ---- layer-0 inputs: relu(x*siW+sib), packed dword writes, conflict-free
    {
        int chp = tid & 31;          // channel pair id
        int grp = tid >> 5;          // 16 groups over 512 (seq,t) pairs
        int ch  = chp << 1;
        float w0 = siW[ch], w1 = siW[ch + 1];
        float b0 = sib[ch], b1 = sib[ch + 1];
        #pragma unroll 4
        for (int it = 0; it < 32; ++it) {
            int p = grp + (it << 4);
            int s = p >> 5, t = p & 31;
            float xv = xs[s * 33 + t];
            float v0 = fmaxf(fmaf(xv, w0, b0), 0.0f);
            float v1 = fmaxf(fmaf(xv, w1, b1), 0.0f);
            int idx = (t << 10) + (s << 6) + ((((ch >> 3) ^ (s & 7))) << 3) + (ch & 7);
            *reinterpret_cast<unsigned int*>(&hseq[idx]) = pack_trunc(v0, v1);
        }
    }

    // hoisted write indices for this wave's 2 (row,col) gate elements
    int wIdx[2];
    #pragma unroll
    for (int k = 0; k < 2; ++k) {
        int row = quad * 4 + ih * 2 + k;
        wIdx[k] = (row << 6) + ((((col >> 3) ^ (row & 7))) << 3) + (col & 7);
    }

    __syncthreads();

    bf16x8 a0 = ld_afrag(hseq, c, quad, 0);   // layer-0 input, t=0 (relu'd)
    bf16x8 a1 = ld_afrag(hseq, c, quad, 1);

    for (int l = 0; l < 4; ++l) {
        // 12 coalesced 16B fragment loads from prepped (pre-scaled) ws
        bf16x8 BiR[2], BiZ[2], BiN[2], BhR[2], BhZ[2], BhN[2];
        #pragma unroll
        for (int kc = 0; kc < 2; ++kc) {
            int base = (l * 6 * 4 + jt) * 128 + kc * 64 + lane;  // mat stride 512
            BiR[kc] = as_frag(wf[base]);
            BiZ[kc] = as_frag(wf[base + 512]);
            BiN[kc] = as_frag(wf[base + 1024]);
            BhR[kc] = as_frag(wf[base + 1536]);
            BhZ[kc] = as_frag(wf[base + 2048]);
            BhN[kc] = as_frag(wf[base + 2560]);
        }
        // biases carry the same folded scales
        float bRs  = NLOG2E  * (bih[l * 192 + col]      + bhh[l * 192 + col]);
        float bZs  = NLOG2E  * (bih[l * 192 + 64 + col] + bhh[l * 192 + 64 + col]);
        float bNIs = P2LOG2E * bih[l * 192 + 128 + col];  // n-gate ih/hh separate:
        float bNHs = P2LOG2E * bhh[l * 192 + 128 + col];  // tanh(xg_n + r*hg_n)
        const f32x4 vbR  = (f32x4){bRs,  bRs,  bRs,  bRs};
        const f32x4 vbZ  = (f32x4){bZs,  bZs,  bZs,  bZs};
        const f32x4 vbNI = (f32x4){bNIs, bNIs, bNIs, bNIs};
        const f32x4 vbNH = (f32x4){bNHs, bNHs, bNHs, bNHs};

        float hprev[2] = {0.0f, 0.0f};

        #pragma unroll 2
        for (int t = 0; t < LS; ++t) {
            f32x4 aR  = MFMA16(a0, BiR[0], vbR);
            f32x4 aZ  = MFMA16(a0, BiZ[0], vbZ);
            f32x4 aNI = MFMA16(a0, BiN[0], vbNI);
            aR  = MFMA16(a1, BiR[1], aR);
            aZ  = MFMA16(a1, BiZ[1], aZ);
            aNI = MFMA16(a1, BiN[1], aNI);
            f32x4 aNH = vbNH;
            if (t > 0) {
                const unsigned short* hb = hrec + (((t - 1) & 1) << 10);
                bf16x8 h0 = ld_afrag(hb, c, quad, 0);   // pre-relu recurrent
                bf16x8 h1 = ld_afrag(hb, c, quad, 1);
                aR  = MFMA16(h0, BhR[0], aR);
                aZ  = MFMA16(h0, BhZ[0], aZ);
                aNH = MFMA16(h0, BhN[0], aNH);
                aR  = MFMA16(h1, BhR[1], aR);
                aZ  = MFMA16(h1, BhZ[1], aZ);
                aNH = MFMA16(h1, BhN[1], aNH);
            }
            unsigned short* wb = hseq + (t << 10);
            unsigned short* wr = hrec + ((t & 1) << 10);
            #pragma unroll
            for (int k = 0; k < 2; ++k) {
                int ai = ih * 2 + k;      // this wave's acc elements
                // scales folded into weights: exp2 directly on accumulators
                float r  = __builtin_amdgcn_rcpf(1.0f + __builtin_amdgcn_exp2f(aR[ai]));
                float z  = __builtin_amdgcn_rcpf(1.0f + __builtin_amdgcn_exp2f(aZ[ai]));
                float e  = __builtin_amdgcn_exp2f(fmaf(r, aNH[ai], aNI[ai]));
                float n  = fmaf(-2.0f, __builtin_amdgcn_rcpf(e + 1.0f), 1.0f);
                float hn = fmaf(z, hprev[k] - n, n);
                hprev[k] = hn;
                wr[wIdx[k]] = f2bf_h(hn);                   // pre-relu (recurrence)
                wb[wIdx[k]] = f2bf_h(fmaxf(hn, 0.0f));      // relu'd (next layer)
            }
            // prefetch next input: slot t+1 untouched this step; at t=31 slot 0
            // already holds this layer's relu'd t=0 output = next layer's input
            const unsigned short* nb = hseq + (((t + 1) & 31) << 10);
            a0 = ld_afrag(nb, c, quad, 0);
            a1 = ld_afrag(nb, c, quad, 1);
            __syncthreads();
        }
    }

    // ---- fused epilogue ----
    // E1 (waves 0-3): slow_feat = hseq[31] (relu'd) @ soW + sob -> stage slot 0
    if (wid < 4) {
        bf16x8 e0 = ld_afrag(hseq + (31 << 10), c, quad, 0);
        bf16x8 e1 = ld_afrag(hseq + (31 << 10), c, quad, 1);
        bf16x8 Bso[2];
        #pragma unroll
        for (int kc = 0; kc < 2; ++kc)
            Bso[kc] = as_frag(wf[(96 + jt) * 128 + kc * 64 + lane]);
        float sb = sob[col];
        f32x4 accS = (f32x4){sb, sb, sb, sb};
        accS = MFMA16(e0, Bso[0], accS);
        accS = MFMA16(e1, Bso[1], accS);
        #pragma unroll
        for (int i = 0; i < 4; ++i) {
            int row = quad * 4 + i;
            int idx = (row << 6) + ((((col >> 3) ^ (row & 7))) << 3) + (col & 7);
            hseq[idx] = f2bf_h(accS[i]);     // slot 0 dead: stage slow_feat
        }
    }
    __syncthreads();
    // E2 (waves 4-7): eps = sf @ s2sW + s2sb -> A_s | g_s
    if (wid >= 4) {
        bf16x8 s0 = ld_afrag(hseq, c, quad, 0);
        bf16x8 s1 = ld_afrag(hseq, c, quad, 1);
        bf16x8 Bs2[2];
        #pragma unroll
        for (int kc = 0; kc < 2; ++kc)
            Bs2[kc] = as_frag(wf[(100 + jt) * 128 + kc * 64 + lane]);
        float eb = (jt < 2) ? NLOG2E * s2sb[col] : s2sb[col];
        f32x4 accE = (f32x4){eb, eb, eb, eb};
        accE = MFMA16(s0, Bs2[0], accE);
        accE = MFMA16(s1, Bs2[1], accE);
        #pragma unroll
        for (int i = 0; i < 4; ++i) {
            int row = quad * 4 + i;
            float v = accE[i];
            AG[row * 65 + col] = (jt < 2)
                ? __builtin_amdgcn_rcpf(1.0f + __builtin_amdgcn_exp2f(v)) : v;
        }
    }
    __syncthreads();
    // E3: fast diagonal SSM + overlap-add (16 frames x 32 ch = 512, one pass)
    {
        int frame = tid >> 5, fch = tid & 31;
        int q = seqbase + frame;
        if (q < BS) {            // skip duplicated clamp frames (no double-add)
            int b  = (q >= ns) ? 1 : 0;
            int fi = q - b * ns;
            float cA = AG[frame * 65 + fch];
            float cG = AG[frame * 65 + 32 + fch];
            float Gf = finW[fch] * cG;
            float Gb = finb[fch] * cG;
            float cFo = foutW[fch];
            float cfb = foutb[0];
            float h = 0.0f;
            const float* xrow = xs + frame * 33;
            float* op = out + (size_t)b * T + fi * DS;
            #pragma unroll 1
            for (int t = 0; t < LS; ++t) {
                h = fmaf(cA, h, fmaf(xrow[t], Gf, Gb));
                float s = h * cFo;
                s += __shfl_xor(s, 1);
                s += __shfl_xor(s, 2);
                s += __shfl_xor(s, 4);
                s += __shfl_xor(s, 8);
                s += __shfl_xor(s, 16);
                if (fch == 0) atomicAdd(&op[t], s + cfb);
            }
        }
    }
}

extern "C" void kernel_launch(void* const* d_in, const int* in_sizes, int n_in,
                              void* d_out, int out_size, void* d_ws, size_t ws_size,
                              hipStream_t stream)
{
    (void)n_in; (void)ws_size;
    const float* x     = (const float*)d_in[0];
    const float* siW   = (const float*)d_in[1];
    const float* sib   = (const float*)d_in[2];
    const float* Wih   = (const float*)d_in[3];
    const float* Whh   = (const float*)d_in[4];
    const float* bih   = (const float*)d_in[5];
    const float* bhh   = (const float*)d_in[6];
    const float* soW   = (const float*)d_in[7];
    const float* sob   = (const float*)d_in[8];
    const float* s2sW  = (const float*)d_in[9];
    const float* s2sb  = (const float*)d_in[10];
    const float* finW  = (const float*)d_in[11];
    const float* finb  = (const float*)d_in[12];
    const float* foutW = (const float*)d_in[13];
    const float* foutb = (const float*)d_in[14];

    int T  = in_sizes[0] / 2;          // B = 2
    int ns = (T - LS) / DS + 1;        // 3999
    int BS = 2 * ns;                   // 7998

    unsigned short* wsW = (unsigned short*)d_ws;   // 104*1024 bf16 = 208 KB

    (void)hipMemsetAsync(d_out, 0, (size_t)out_size * sizeof(float), stream);

    prep_weights<<<dim3(416), dim3(256), 0, stream>>>(Wih, Whh, soW, s2sW, wsW);

    slowfast_fused<<<dim3((BS + 15) / 16), dim3(512), 0, stream>>>(
        x, siW, sib, bih, bhh, sob, s2sb, finW, finb, foutW, foutb,
        wsW, (float*)d_out, T, ns, BS);
}

// Round 12
// 175.426 us; speedup vs baseline: 1.1160x; 1.1160x over previous
//
#include <hip/hip_runtime.h>

#define GH 64
#define LS 32
#define HF 32
#define DS 16

// transcendental folding constants (exact fp32 rescale of weights at prep)
#define NLOG2E -1.4426950408889634f   // r,z columns:  sigm(x)=rcp(1+exp2(-log2e*x))
#define P2LOG2E 2.8853900817779268f   // n columns:    tanh(x)=(C-1)/(C+1), C=exp2(2log2e*x)

typedef short bf16x8 __attribute__((ext_vector_type(8)));
typedef float f32x4 __attribute__((ext_vector_type(4)));

#define MFMA16(a, b, c) __builtin_amdgcn_mfma_f32_16x16x32_bf16(a, b, c, 0, 0, 0)

__device__ __forceinline__ unsigned int f2bf_rne(float f) {
    unsigned int u = __float_as_uint(f);
    return (u + 0x7FFFu + ((u >> 16) & 1u)) >> 16;   // RNE (prep kernel only)
}
__device__ __forceinline__ unsigned short f2bf_h(float f) {
    return (unsigned short)((__float_as_uint(f) + 0x8000u) >> 16);  // half-up
}
__device__ __forceinline__ unsigned int pack_trunc(float v0, float v1) {
    return __builtin_amdgcn_perm(__float_as_uint(v1), __float_as_uint(v0),
                                 0x07060302u);   // (bf16(v1)<<16)|bf16(v0)
}
__device__ __forceinline__ bf16x8 as_frag(uint4 u) {
    union { uint4 a; bf16x8 b; } cv; cv.a = u; return cv.b;
}

// A-fragment from one 16x64 bf16 slot, XOR-swizzled 16B blocks:
// (seq,ch) at seq*64 + (((ch>>3)^(seq&7))<<3) + (ch&7). Conflict-free b128.
__device__ __forceinline__ bf16x8 ld_afrag(const unsigned short* slot, int m,
                                           int quad, int half) {
    int b   = half * 4 + quad;
    int idx = (m << 6) + ((b ^ (m & 7)) << 3);
    return as_frag(*reinterpret_cast<const uint4*>(slot + idx));
}

// ---- prep: fp32 weights -> bf16 MFMA B-fragments, fragment-ordered, with
// transcendental scales FOLDED IN; also zeroes d_out (memset dispatch merged).
// idx = rest*1024 + kc*512 + lane*8 + j.
// GRU (rest<96): rest=(l*6+mat)*4+jt, mat 0..2 = Wih r/z/n, 3..5 = Whh r/z/n.
// Epi (rest=96..103): rest=96+m2*4+jt, m2: 0=soW (unscaled), 1=s2sW.
__global__ __launch_bounds__(256) void prep_weights(
    const float* __restrict__ Wih, const float* __restrict__ Whh,
    const float* __restrict__ soW, const float* __restrict__ s2sW,
    unsigned short* __restrict__ wsW, float* __restrict__ out, int outN)
{
    int idx = blockIdx.x * 256 + threadIdx.x;
    if (idx < outN) out[idx] = 0.0f;              // fused d_out zeroing
    if (idx >= 104 * 1024) return;
    int j = idx & 7, lane = (idx >> 3) & 63, kc = (idx >> 9) & 1, rest = idx >> 10;
    int k = kc * 32 + ((lane >> 4) << 3) + j;
    int c = lane & 15;
    float v;
    if (rest < 96) {
        int jt = rest & 3, mt = rest >> 2;
        int l = mt / 6, mat = mt - l * 6;
        int col = jt * 16 + c;
        const float* W = (mat < 3) ? Wih + (size_t)l * GH * 192
                                   : Whh + (size_t)l * GH * 192;
        int m3 = (mat < 3) ? mat : mat - 3;
        v = W[k * 192 + m3 * 64 + col];
        v *= (m3 == 2) ? P2LOG2E : NLOG2E;       // fold trans scale
    } else {
        int r2 = rest - 96;
        int jt = r2 & 3, m2 = r2 >> 2;
        int col = jt * 16 + c;
        v = (m2 ? s2sW : soW)[k * 64 + col];
        if (m2 && jt < 2) v *= NLOG2E;           // A_s sigmoid half
    }
    wsW[idx] = (unsigned short)f2bf_rne(v);
}

// Block = 4 waves x 64 (wave jt owns gate cols [jt*16,jt*16+16)); 16 seqs.
// hseq: RELU'D h (next-layer input), in-place across layers, 64 KB.
// hrec: PRE-relu h, 2-slot ping-pong (recurrence needs only t-1), 4 KB.
// One barrier/step; a(t+1) prefetched pre-barrier. Weights pre-scaled so exp2
// applies directly to the MFMA accumulator. Gate update uses the fused form
//   hn = [B(C-1) + h(C+1)] * rcp[(1+B)(C+1)]   (z & tanh share one rcp)
// -> 5 transcendentals/element instead of 6 (trans issue = the measured
// bottleneck: ~85% of VALU busy). Fused epilogue + fast SSM, 2 dispatches.
__global__ __launch_bounds__(256, 2) void slowfast_fused(
    const float* __restrict__ x,
    const float* __restrict__ siW,  const float* __restrict__ sib,
    const float* __restrict__ bih,  const float* __restrict__ bhh,
    const float* __restrict__ sob,  const float* __restrict__ s2sb,
    const float* __restrict__ finW, const float* __restrict__ finb,
    const float* __restrict__ foutW, const float* __restrict__ foutb,
    const unsigned short* __restrict__ wsW,
    float* __restrict__ out,
    int T, int ns, int BS)
{
    __shared__ __align__(16) unsigned short hseq[LS * 16 * 64];  // 64 KB
    __shared__ __align__(16) unsigned short hrec[2 * 16 * 64];   // 4 KB
    __shared__ float xs[16 * 33];    // x windows (pad-33)
    __shared__ float AG[16 * 65];    // A_s | g_s staging (pad-65)

    const int tid  = threadIdx.x;
    const int lane = tid & 63;
    const int jt   = tid >> 6;
    const int c    = lane & 15;
    const int quad = lane >> 4;
    const int col  = jt * 16 + c;
    const int seqbase = blockIdx.x * 16;
    const uint4* wf = reinterpret_cast<const uint4*>(wsW);

    // ---- stage x windows ----
    for (int p = tid; p < 512; p += 256) {           // p = seq*32 + t
        int seq = p >> 5, t = p & 31;
        int q = seqbase + seq; if (q > BS - 1) q = BS - 1;
        int b  = (q >= ns) ? 1 : 0;
        int si = q - b * ns;
        xs[seq * 33 + t] = x[b * T + si * DS + t];
    }
    __syncthreads();

    // ---- layer-0 inputs: relu(x*siW+sib), packed dword writes, conflict-free
    {
        int chp = tid & 31;          // channel pair id
        int grp = tid >> 5;          // 8 groups over 512 (seq,t) pairs
        int ch  = chp << 1;
        float w0 = siW[ch], w1 = siW[ch + 1];
        float b0 = sib[ch], b1 = sib[ch + 1];
        #pragma unroll 4
        for (int it = 0; it < 64; ++it) {
            int p = grp + (it << 3);
            int s = p >> 5, t = p & 31;
            float xv = xs[s * 33 + t];
            float v0 = fmaxf(fmaf(xv, w0, b0), 0.0f);
            float v1 = fmaxf(fmaf(xv, w1, b1), 0.0f);
            int idx = (t << 10) + (s << 6) + ((((ch >> 3) ^ (s & 7))) << 3) + (ch & 7);
            *reinterpret_cast<unsigned int*>(&hseq[idx]) = pack_trunc(v0, v1);
        }
    }

    // hoisted write indices for this lane's 4 (row,col) gate elements
    int wIdx[4];
    #pragma unroll
    for (int i = 0; i < 4; ++i) {
        int row = quad * 4 + i;
        wIdx[i] = (row << 6) + ((((col >> 3) ^ (row & 7))) << 3) + (col & 7);
    }

    __syncthreads();

    bf16x8 a0 = ld_afrag(hseq, c, quad, 0);   // layer-0 input, t=0 (relu'd)
    bf16x8 a1 = ld_afrag(hseq, c, quad, 1);

    for (int l = 0; l < 4; ++l) {
        // 12 coalesced 16B fragment loads from prepped (pre-scaled) ws
        bf16x8 BiR[2], BiZ[2], BiN[2], BhR[2], BhZ[2], BhN[2];
        #pragma unroll
        for (int kc = 0; kc < 2; ++kc) {
            int base = (l * 6 * 4 + jt) * 128 + kc * 64 + lane;  // mat stride 512
            BiR[kc] = as_frag(wf[base]);
            BiZ[kc] = as_frag(wf[base + 512]);
            BiN[kc] = as_frag(wf[base + 1024]);
            BhR[kc] = as_frag(wf[base + 1536]);
            BhZ[kc] = as_frag(wf[base + 2048]);
            BhN[kc] = as_frag(wf[base + 2560]);
        }
        // biases carry the same folded scales
        float bRs  = NLOG2E  * (bih[l * 192 + col]      + bhh[l * 192 + col]);
        float bZs  = NLOG2E  * (bih[l * 192 + 64 + col] + bhh[l * 192 + 64 + col]);
        float bNIs = P2LOG2E * bih[l * 192 + 128 + col];  // n-gate ih/hh separate:
        float bNHs = P2LOG2E * bhh[l * 192 + 128 + col];  // tanh(xg_n + r*hg_n)
        const f32x4 vbR  = (f32x4){bRs,  bRs,  bRs,  bRs};
        const f32x4 vbZ  = (f32x4){bZs,  bZs,  bZs,  bZs};
        const f32x4 vbNI = (f32x4){bNIs, bNIs, bNIs, bNIs};
        const f32x4 vbNH = (f32x4){bNHs, bNHs, bNHs, bNHs};

        float hprev[4] = {0.0f, 0.0f, 0.0f, 0.0f};

        #pragma unroll 2
        for (int t = 0; t < LS; ++t) {
            f32x4 aR  = MFMA16(a0, BiR[0], vbR);
            f32x4 aZ  = MFMA16(a0, BiZ[0], vbZ);
            f32x4 aNI = MFMA16(a0, BiN[0], vbNI);
            aR  = MFMA16(a1, BiR[1], aR);
            aZ  = MFMA16(a1, BiZ[1], aZ);
            aNI = MFMA16(a1, BiN[1], aNI);
            f32x4 aNH = vbNH;
            if (t > 0) {
                const unsigned short* hb = hrec + (((t - 1) & 1) << 10);
                bf16x8 h0 = ld_afrag(hb, c, quad, 0);   // pre-relu recurrent
                bf16x8 h1 = ld_afrag(hb, c, quad, 1);
                aR  = MFMA16(h0, BhR[0], aR);
                aZ  = MFMA16(h0, BhZ[0], aZ);
                aNH = MFMA16(h0, BhN[0], aNH);
                aR  = MFMA16(h1, BhR[1], aR);
                aZ  = MFMA16(h1, BhZ[1], aZ);
                aNH = MFMA16(h1, BhN[1], aNH);
            }
            unsigned short* wb = hseq + (t << 10);
            unsigned short* wr = hrec + ((t & 1) << 10);
            #pragma unroll
            for (int i = 0; i < 4; ++i) {
                // A=e^{-xr}, B=e^{-xz}, C=e^{2xn}; r=1/(1+A);
                // hn = (1-z)*tanh + z*h = [B(C-1)+h(C+1)] / [(1+B)(C+1)]
                float A = __builtin_amdgcn_exp2f(aR[i]);
                float r = __builtin_amdgcn_rcpf(1.0f + A);
                float B = __builtin_amdgcn_exp2f(aZ[i]);
                float C = __builtin_amdgcn_exp2f(fmaf(r, aNH[i], aNI[i]));
                float Cp = C + 1.0f;
                float num = fmaf(hprev[i], Cp, B * (C - 1.0f));
                float den = (1.0f + B) * Cp;
                float hn  = num * __builtin_amdgcn_rcpf(den);
                hprev[i] = hn;
                wr[wIdx[i]] = f2bf_h(hn);                   // pre-relu (recurrence)
                wb[wIdx[i]] = f2bf_h(fmaxf(hn, 0.0f));      // relu'd (next layer)
            }
            // prefetch next input: slot t+1 untouched this step; at t=31 slot 0
            // already holds this layer's relu'd t=0 output = next layer's input
            const unsigned short* nb = hseq + (((t + 1) & 31) << 10);
            a0 = ld_afrag(nb, c, quad, 0);
            a1 = ld_afrag(nb, c, quad, 1);
            __syncthreads();
        }
    }

    // ---- fused epilogue ----
    {   // E1: slow_feat = hseq[31] (already relu'd) @ soW + sob -> stage slot 0
        bf16x8 e0 = ld_afrag(hseq + (31 << 10), c, quad, 0);
        bf16x8 e1 = ld_afrag(hseq + (31 << 10), c, quad, 1);
        bf16x8 Bso[2], Bs2[2];
        #pragma unroll
        for (int kc = 0; kc < 2; ++kc) {
            Bso[kc] = as_frag(wf[(96 + jt)  * 128 + kc * 64 + lane]);
            Bs2[kc] = as_frag(wf[(100 + jt) * 128 + kc * 64 + lane]);
        }
        float sb = sob[col];
        f32x4 accS = (f32x4){sb, sb, sb, sb};
        accS = MFMA16(e0, Bso[0], accS);
        accS = MFMA16(e1, Bso[1], accS);
        #pragma unroll
        for (int i = 0; i < 4; ++i)
            hseq[wIdx[i]] = f2bf_h(accS[i]);     // slot 0 dead: stage slow_feat
        __syncthreads();
        // E2: eps = sf @ s2sW + s2sb -> A_s | g_s (A half pre-scaled by -log2e)
        bf16x8 s0 = ld_afrag(hseq, c, quad, 0);
        bf16x8 s1 = ld_afrag(hseq, c, quad, 1);
        float eb = (jt < 2) ? NLOG2E * s2sb[col] : s2sb[col];
        f32x4 accE = (f32x4){eb, eb, eb, eb};
        accE = MFMA16(s0, Bs2[0], accE);
        accE = MFMA16(s1, Bs2[1], accE);
        #pragma unroll
        for (int i = 0; i < 4; ++i) {
            int row = quad * 4 + i;
            float v = accE[i];
            AG[row * 65 + col] = (jt < 2)
                ? __builtin_amdgcn_rcpf(1.0f + __builtin_amdgcn_exp2f(v)) : v;
        }
    }
    __syncthreads();
    // E3: fast diagonal SSM + overlap-add (16 frames x 32 ch, 2 passes)
    {
        int fch = tid & 31;
        float Gfw = finW[fch], Gbw = finb[fch], cFo = foutW[fch], cfb = foutb[0];
        #pragma unroll
        for (int half = 0; half < 2; ++half) {
            int frame = half * 8 + (tid >> 5);
            int q = seqbase + frame;
            if (q < BS) {        // skip duplicated clamp frames (no double-add)
                int b  = (q >= ns) ? 1 : 0;
                int fi = q - b * ns;
                float cA = AG[frame * 65 + fch];
                float cG = AG[frame * 65 + 32 + fch];
                float Gf = Gfw * cG;
                float Gb = Gbw * cG;
                float h = 0.0f;
                const float* xrow = xs + frame * 33;
                float* op = out + (size_t)b * T + fi * DS;
                #pragma unroll 1
                for (int t = 0; t < LS; ++t) {
                    h = fmaf(cA, h, fmaf(xrow[t], Gf, Gb));
                    float s = h * cFo;
                    s += __shfl_xor(s, 1);
                    s += __shfl_xor(s, 2);
                    s += __shfl_xor(s, 4);
                    s += __shfl_xor(s, 8);
                    s += __shfl_xor(s, 16);
                    if (fch == 0) atomicAdd(&op[t], s + cfb);
                }
            }
        }
    }
}

extern "C" void kernel_launch(void* const* d_in, const int* in_sizes, int n_in,
                              void* d_out, int out_size, void* d_ws, size_t ws_size,
                              hipStream_t stream)
{
    (void)n_in; (void)ws_size;
    const float* x     = (const float*)d_in[0];
    const float* siW   = (const float*)d_in[1];
    const float* sib   = (const float*)d_in[2];
    const float* Wih   = (const float*)d_in[3];
    const float* Whh   = (const float*)d_in[4];
    const float* bih   = (const float*)d_in[5];
    const float* bhh   = (const float*)d_in[6];
    const float* soW   = (const float*)d_in[7];
    const float* sob   = (const float*)d_in[8];
    const float* s2sW  = (const float*)d_in[9];
    const float* s2sb  = (const float*)d_in[10];
    const float* finW  = (const float*)d_in[11];
    const float* finb  = (const float*)d_in[12];
    const float* foutW = (const float*)d_in[13];
    const float* foutb = (const float*)d_in[14];

    int T  = in_sizes[0] / 2;          // B = 2
    int ns = (T - LS) / DS + 1;        // 3999
    int BS = 2 * ns;                   // 7998

    unsigned short* wsW = (unsigned short*)d_ws;   // 104*1024 bf16 = 208 KB

    // 500 blocks x 256 = 128000 threads: covers out_size (2*64000) zeroing
    prep_weights<<<dim3(500), dim3(256), 0, stream>>>(
        Wih, Whh, soW, s2sW, wsW, (float*)d_out, out_size);

    slowfast_fused<<<dim3((BS + 15) / 16), dim3(256), 0, stream>>>(
        x, siW, sib, bih, bhh, sob, s2sb, finW, finb, foutW, foutb,
        wsW, (float*)d_out, T, ns, BS);
}

// Round 13
// 172.049 us; speedup vs baseline: 1.1379x; 1.0196x over previous
//
#include <hip/hip_runtime.h>

#define GH 64
#define LS 32
#define HF 32
#define DS 16

// transcendental folding constants (exact fp32 rescale of weights at prep)
#define NLOG2E -1.4426950408889634f   // r,z columns:  sigm(x)=rcp(1+exp2(-log2e*x))
#define P2LOG2E 2.8853900817779268f   // n columns:    tanh(x)=1-2*rcp(exp2(2log2e*x)+1)

typedef short bf16x8 __attribute__((ext_vector_type(8)));
typedef float f32x4 __attribute__((ext_vector_type(4)));

#define MFMA16(a, b, c) __builtin_amdgcn_mfma_f32_16x16x32_bf16(a, b, c, 0, 0, 0)

__device__ __forceinline__ unsigned int f2bf_rne(float f) {
    unsigned int u = __float_as_uint(f);
    return (u + 0x7FFFu + ((u >> 16) & 1u)) >> 16;   // RNE (prep kernel only)
}
__device__ __forceinline__ unsigned short f2bf_h(float f) {
    return (unsigned short)((__float_as_uint(f) + 0x8000u) >> 16);  // half-up
}
__device__ __forceinline__ unsigned int pack_trunc(float v0, float v1) {
    return __builtin_amdgcn_perm(__float_as_uint(v1), __float_as_uint(v0),
                                 0x07060302u);   // (bf16(v1)<<16)|bf16(v0)
}
__device__ __forceinline__ bf16x8 as_frag(uint4 u) {
    union { uint4 a; bf16x8 b; } cv; cv.a = u; return cv.b;
}

// A-fragment from one 16x64 bf16 slot, XOR-swizzled 16B blocks:
// (seq,ch) at seq*64 + (((ch>>3)^(seq&7))<<3) + (ch&7). Conflict-free b128.
__device__ __forceinline__ bf16x8 ld_afrag(const unsigned short* slot, int m,
                                           int quad, int half) {
    int b   = half * 4 + quad;
    int idx = (m << 6) + ((b ^ (m & 7)) << 3);
    return as_frag(*reinterpret_cast<const uint4*>(slot + idx));
}

// ---- prep: fp32 weights -> bf16 MFMA B-fragments, fragment-ordered, with
// transcendental scales FOLDED IN; also zeroes d_out (memset dispatch merged).
// idx = rest*1024 + kc*512 + lane*8 + j.
// GRU (rest<96): rest=(l*6+mat)*4+jt, mat 0..2 = Wih r/z/n, 3..5 = Whh r/z/n.
// Epi (rest=96..103): rest=96+m2*4+jt, m2: 0=soW (unscaled), 1=s2sW.
__global__ __launch_bounds__(256) void prep_weights(
    const float* __restrict__ Wih, const float* __restrict__ Whh,
    const float* __restrict__ soW, const float* __restrict__ s2sW,
    unsigned short* __restrict__ wsW, float* __restrict__ out, int outN)
{
    int idx = blockIdx.x * 256 + threadIdx.x;
    if (idx < outN) out[idx] = 0.0f;              // fused d_out zeroing
    if (idx >= 104 * 1024) return;
    int j = idx & 7, lane = (idx >> 3) & 63, kc = (idx >> 9) & 1, rest = idx >> 10;
    int k = kc * 32 + ((lane >> 4) << 3) + j;
    int c = lane & 15;
    float v;
    if (rest < 96) {
        int jt = rest & 3, mt = rest >> 2;
        int l = mt / 6, mat = mt - l * 6;
        int col = jt * 16 + c;
        const float* W = (mat < 3) ? Wih + (size_t)l * GH * 192
                                   : Whh + (size_t)l * GH * 192;
        int m3 = (mat < 3) ? mat : mat - 3;
        v = W[k * 192 + m3 * 64 + col];
        v *= (m3 == 2) ? P2LOG2E : NLOG2E;       // fold trans scale
    } else {
        int r2 = rest - 96;
        int jt = r2 & 3, m2 = r2 >> 2;
        int col = jt * 16 + c;
        v = (m2 ? s2sW : soW)[k * 64 + col];
        if (m2 && jt < 2) v *= NLOG2E;           // A_s sigmoid half
    }
    wsW[idx] = (unsigned short)f2bf_rne(v);
}

// Block = 4 waves x 64 (wave jt owns gate cols [jt*16,jt*16+16)); 16 seqs.
// hseq: RELU'D h (next-layer input), in-place across layers, 64 KB.
// hrec: PRE-relu h, 2-slot ping-pong (recurrence needs only t-1), 4 KB.
// One barrier/step; a(t+1) prefetched pre-barrier. Weights pre-scaled so exp2
// applies directly to the MFMA accumulator. Gate math uses the R9 form
// (6 trans, z-chain INDEPENDENT of r-chain): measured faster than the
// 5-trans fused form (R12) because ILP across the 4 elements' chains beats
// op count at 2 waves/SIMD. Fused epilogue + fast SSM; 2 dispatches total.
__global__ __launch_bounds__(256, 2) void slowfast_fused(
    const float* __restrict__ x,
    const float* __restrict__ siW,  const float* __restrict__ sib,
    const float* __restrict__ bih,  const float* __restrict__ bhh,
    const float* __restrict__ sob,  const float* __restrict__ s2sb,
    const float* __restrict__ finW, const float* __restrict__ finb,
    const float* __restrict__ foutW, const float* __restrict__ foutb,
    const unsigned short* __restrict__ wsW,
    float* __restrict__ out,
    int T, int ns, int BS)
{
    __shared__ __align__(16) unsigned short hseq[LS * 16 * 64];  // 64 KB
    __shared__ __align__(16) unsigned short hrec[2 * 16 * 64];   // 4 KB
    __shared__ float xs[16 * 33];    // x windows (pad-33)
    __shared__ float AG[16 * 65];    // A_s | g_s staging (pad-65)

    const int tid  = threadIdx.x;
    const int lane = tid & 63;
    const int jt   = tid >> 6;
    const int c    = lane & 15;
    const int quad = lane >> 4;
    const int col  = jt * 16 + c;
    const int seqbase = blockIdx.x * 16;
    const uint4* wf = reinterpret_cast<const uint4*>(wsW);

    // ---- stage x windows ----
    for (int p = tid; p < 512; p += 256) {           // p = seq*32 + t
        int seq = p >> 5, t = p & 31;
        int q = seqbase + seq; if (q > BS - 1) q = BS - 1;
        int b  = (q >= ns) ? 1 : 0;
        int si = q - b * ns;
        xs[seq * 33 + t] = x[b * T + si * DS + t];
    }
    __syncthreads();

    // ---- layer-0 inputs: relu(x*siW+sib), packed dword writes, conflict-free
    {
        int chp = tid & 31;          // channel pair id
        int grp = tid >> 5;          // 8 groups over 512 (seq,t) pairs
        int ch  = chp << 1;
        float w0 = siW[ch], w1 = siW[ch + 1];
        float b0 = sib[ch], b1 = sib[ch + 1];
        #pragma unroll 4
        for (int it = 0; it < 64; ++it) {
            int p = grp + (it << 3);
            int s = p >> 5, t = p & 31;
            float xv = xs[s * 33 + t];
            float v0 = fmaxf(fmaf(xv, w0, b0), 0.0f);
            float v1 = fmaxf(fmaf(xv, w1, b1), 0.0f);
            int idx = (t << 10) + (s << 6) + ((((ch >> 3) ^ (s & 7))) << 3) + (ch & 7);
            *reinterpret_cast<unsigned int*>(&hseq[idx]) = pack_trunc(v0, v1);
        }
    }

    // hoisted write indices for this lane's 4 (row,col) gate elements
    int wIdx[4];
    #pragma unroll
    for (int i = 0; i < 4; ++i) {
        int row = quad * 4 + i;
        wIdx[i] = (row << 6) + ((((col >> 3) ^ (row & 7))) << 3) + (col & 7);
    }

    __syncthreads();

    bf16x8 a0 = ld_afrag(hseq, c, quad, 0);   // layer-0 input, t=0 (relu'd)
    bf16x8 a1 = ld_afrag(hseq, c, quad, 1);

    for (int l = 0; l < 4; ++l) {
        // 12 coalesced 16B fragment loads from prepped (pre-scaled) ws
        bf16x8 BiR[2], BiZ[2], BiN[2], BhR[2], BhZ[2], BhN[2];
        #pragma unroll
        for (int kc = 0; kc < 2; ++kc) {
            int base = (l * 6 * 4 + jt) * 128 + kc * 64 + lane;  // mat stride 512
            BiR[kc] = as_frag(wf[base]);
            BiZ[kc] = as_frag(wf[base + 512]);
            BiN[kc] = as_frag(wf[base + 1024]);
            BhR[kc] = as_frag(wf[base + 1536]);
            BhZ[kc] = as_frag(wf[base + 2048]);
            BhN[kc] = as_frag(wf[base + 2560]);
        }
        // biases carry the same folded scales
        float bRs  = NLOG2E  * (bih[l * 192 + col]      + bhh[l * 192 + col]);
        float bZs  = NLOG2E  * (bih[l * 192 + 64 + col] + bhh[l * 192 + 64 + col]);
        float bNIs = P2LOG2E * bih[l * 192 + 128 + col];  // n-gate ih/hh separate:
        float bNHs = P2LOG2E * bhh[l * 192 + 128 + col];  // tanh(xg_n + r*hg_n)
        const f32x4 vbR  = (f32x4){bRs,  bRs,  bRs,  bRs};
        const f32x4 vbZ  = (f32x4){bZs,  bZs,  bZs,  bZs};
        const f32x4 vbNI = (f32x4){bNIs, bNIs, bNIs, bNIs};
        const f32x4 vbNH = (f32x4){bNHs, bNHs, bNHs, bNHs};

        float hprev[4] = {0.0f, 0.0f, 0.0f, 0.0f};

        #pragma unroll 2
        for (int t = 0; t < LS; ++t) {
            f32x4 aR  = MFMA16(a0, BiR[0], vbR);
            f32x4 aZ  = MFMA16(a0, BiZ[0], vbZ);
            f32x4 aNI = MFMA16(a0, BiN[0], vbNI);
            aR  = MFMA16(a1, BiR[1], aR);
            aZ  = MFMA16(a1, BiZ[1], aZ);
            aNI = MFMA16(a1, BiN[1], aNI);
            f32x4 aNH = vbNH;
            if (t > 0) {
                const unsigned short* hb = hrec + (((t - 1) & 1) << 10);
                bf16x8 h0 = ld_afrag(hb, c, quad, 0);   // pre-relu recurrent
                bf16x8 h1 = ld_afrag(hb, c, quad, 1);
                aR  = MFMA16(h0, BhR[0], aR);
                aZ  = MFMA16(h0, BhZ[0], aZ);
                aNH = MFMA16(h0, BhN[0], aNH);
                aR  = MFMA16(h1, BhR[1], aR);
                aZ  = MFMA16(h1, BhZ[1], aZ);
                aNH = MFMA16(h1, BhN[1], aNH);
            }
            unsigned short* wb = hseq + (t << 10);
            unsigned short* wr = hrec + ((t & 1) << 10);
            #pragma unroll
            for (int i = 0; i < 4; ++i) {
                // R9 gate form: independent r and z chains (best measured ILP)
                float r  = __builtin_amdgcn_rcpf(1.0f + __builtin_amdgcn_exp2f(aR[i]));
                float z  = __builtin_amdgcn_rcpf(1.0f + __builtin_amdgcn_exp2f(aZ[i]));
                float e  = __builtin_amdgcn_exp2f(fmaf(r, aNH[i], aNI[i]));
                float n  = fmaf(-2.0f, __builtin_amdgcn_rcpf(e + 1.0f), 1.0f);
                float hn = fmaf(z, hprev[i] - n, n);
                hprev[i] = hn;
                wr[wIdx[i]] = f2bf_h(hn);                   // pre-relu (recurrence)
                wb[wIdx[i]] = f2bf_h(fmaxf(hn, 0.0f));      // relu'd (next layer)
            }
            // prefetch next input: slot t+1 untouched this step; at t=31 slot 0
            // already holds this layer's relu'd t=0 output = next layer's input
            const unsigned short* nb = hseq + (((t + 1) & 31) << 10);
            a0 = ld_afrag(nb, c, quad, 0);
            a1 = ld_afrag(nb, c, quad, 1);
            __syncthreads();
        }
    }

    // ---- fused epilogue ----
    {   // E1: slow_feat = hseq[31] (already relu'd) @ soW + sob -> stage slot 0
        bf16x8 e0 = ld_afrag(hseq + (31 << 10), c, quad, 0);
        bf16x8 e1 = ld_afrag(hseq + (31 << 10), c, quad, 1);
        bf16x8 Bso[2], Bs2[2];
        #pragma unroll
        for (int kc = 0; kc < 2; ++kc) {
            Bso[kc] = as_frag(wf[(96 + jt)  * 128 + kc * 64 + lane]);
            Bs2[kc] = as_frag(wf[(100 + jt) * 128 + kc * 64 + lane]);
        }
        float sb = sob[col];
        f32x4 accS = (f32x4){sb, sb, sb, sb};
        accS = MFMA16(e0, Bso[0], accS);
        accS = MFMA16(e1, Bso[1], accS);
        #pragma unroll
        for (int i = 0; i < 4; ++i)
            hseq[wIdx[i]] = f2bf_h(accS[i]);     // slot 0 dead: stage slow_feat
        __syncthreads();
        // E2: eps = sf @ s2sW + s2sb -> A_s | g_s (A half pre-scaled by -log2e)
        bf16x8 s0 = ld_afrag(hseq, c, quad, 0);
        bf16x8 s1 = ld_afrag(hseq, c, quad, 1);
        float eb = (jt < 2) ? NLOG2E * s2sb[col] : s2sb[col];
        f32x4 accE = (f32x4){eb, eb, eb, eb};
        accE = MFMA16(s0, Bs2[0], accE);
        accE = MFMA16(s1, Bs2[1], accE);
        #pragma unroll
        for (int i = 0; i < 4; ++i) {
            int row = quad * 4 + i;
            float v = accE[i];
            AG[row * 65 + col] = (jt < 2)
                ? __builtin_amdgcn_rcpf(1.0f + __builtin_amdgcn_exp2f(v)) : v;
        }
    }
    __syncthreads();
    // E3: fast diagonal SSM + overlap-add (16 frames x 32 ch, 2 passes)
    {
        int fch = tid & 31;
        float Gfw = finW[fch], Gbw = finb[fch], cFo = foutW[fch], cfb = foutb[0];
        #pragma unroll
        for (int half = 0; half < 2; ++half) {
            int frame = half * 8 + (tid >> 5);
            int q = seqbase + frame;
            if (q < BS) {        // skip duplicated clamp frames (no double-add)
                int b  = (q >= ns) ? 1 : 0;
                int fi = q - b * ns;
                float cA = AG[frame * 65 + fch];
                float cG = AG[frame * 65 + 32 + fch];
                float Gf = Gfw * cG;
                float Gb = Gbw * cG;
                float h = 0.0f;
                const float* xrow = xs + frame * 33;
                float* op = out + (size_t)b * T + fi * DS;
                #pragma unroll 1
                for (int t = 0; t < LS; ++t) {
                    h = fmaf(cA, h, fmaf(xrow[t], Gf, Gb));
                    float s = h * cFo;
                    s += __shfl_xor(s, 1);
                    s += __shfl_xor(s, 2);
                    s += __shfl_xor(s, 4);
                    s += __shfl_xor(s, 8);
                    s += __shfl_xor(s, 16);
                    if (fch == 0) atomicAdd(&op[t], s + cfb);
                }
            }
        }
    }
}

extern "C" void kernel_launch(void* const* d_in, const int* in_sizes, int n_in,
                              void* d_out, int out_size, void* d_ws, size_t ws_size,
                              hipStream_t stream)
{
    (void)n_in; (void)ws_size;
    const float* x     = (const float*)d_in[0];
    const float* siW   = (const float*)d_in[1];
    const float* sib   = (const float*)d_in[2];
    const float* Wih   = (const float*)d_in[3];
    const float* Whh   = (const float*)d_in[4];
    const float* bih   = (const float*)d_in[5];
    const float* bhh   = (const float*)d_in[6];
    const float* soW   = (const float*)d_in[7];
    const float* sob   = (const float*)d_in[8];
    const float* s2sW  = (const float*)d_in[9];
    const float* s2sb  = (const float*)d_in[10];
    const float* finW  = (const float*)d_in[11];
    const float* finb  = (const float*)d_in[12];
    const float* foutW = (const float*)d_in[13];
    const float* foutb = (const float*)d_in[14];

    int T  = in_sizes[0] / 2;          // B = 2
    int ns = (T - LS) / DS + 1;        // 3999
    int BS = 2 * ns;                   // 7998

    unsigned short* wsW = (unsigned short*)d_ws;   // 104*1024 bf16 = 208 KB

    // 500 blocks x 256 = 128000 threads: covers out_size (2*64000) zeroing
    prep_weights<<<dim3(500), dim3(256), 0, stream>>>(
        Wih, Whh, soW, s2sW, wsW, (float*)d_out, out_size);

    slowfast_fused<<<dim3((BS + 15) / 16), dim3(256), 0, stream>>>(
        x, siW, sib, bih, bhh, sob, s2sb, finW, finb, foutW, foutb,
        wsW, (float*)d_out, T, ns, BS);
}